// Round 2
// baseline (921.399 us; speedup 1.0000x reference)
//
#include <hip/hip_runtime.h>

typedef short short8 __attribute__((ext_vector_type(8)));
typedef float f32x4 __attribute__((ext_vector_type(4)));

#define D 512
#define KDIM 1024

// ---- bf16 helpers (manual, RNE) ----
static __device__ __forceinline__ unsigned short f2b(float f) {
    unsigned u = __builtin_bit_cast(unsigned, f);
    unsigned r = (u + 0x7fffu + ((u >> 16) & 1u)) >> 16;
    return (unsigned short)r;
}
static __device__ __forceinline__ float b2f(unsigned short u) {
    return __builtin_bit_cast(float, ((unsigned)u) << 16);
}
static __device__ __forceinline__ void split(float v, unsigned short& hi, unsigned short& lo) {
    hi = f2b(v);
    lo = f2b(v - b2f(hi));
}

// ---- build W hi/lo: W[e][k] bf16 pair, k<512 from wl, else wr ----
__global__ void prep_w(const float* __restrict__ wl, const float* __restrict__ wr,
                       unsigned short* __restrict__ Wh, unsigned short* __restrict__ Wl) {
    int t = blockIdx.x * 256 + threadIdx.x;   // over 512*1024
    int e = t >> 10, k = t & 1023;
    float v = (k < 512) ? wl[e * 512 + k] : wr[e * 512 + (k - 512)];
    unsigned short h, l;
    split(v, h, l);
    Wh[t] = h; Wl[t] = l;
}

// ---- child weighted reduce (fp32 in, bf16 hi/lo out) ----
// A[p][0:512]=U, A[p][512:1024]=V ; lc=[1,2/3,1/3,0], rc=[0,1/3,2/3,1]
__global__ void reduce_kernel(const float* __restrict__ child,
                              unsigned short* __restrict__ Ah, unsigned short* __restrict__ Al,
                              int n, int mpad) {
    int t = blockIdx.x * 256 + threadIdx.x;   // mpad*64 threads
    int p = t >> 6;
    int kc = (t & 63) << 3;
    if (p >= mpad) return;
    if (p >= n) {
        short8 z = (short8)0;
        *reinterpret_cast<short8*>(&Ah[(size_t)p * KDIM + kc]) = z;
        *reinterpret_cast<short8*>(&Ah[(size_t)p * KDIM + 512 + kc]) = z;
        *reinterpret_cast<short8*>(&Al[(size_t)p * KDIM + kc]) = z;
        *reinterpret_cast<short8*>(&Al[(size_t)p * KDIM + 512 + kc]) = z;
        return;
    }
    const float c13 = 1.0f / 3.0f, c23 = 2.0f / 3.0f;
    float4 a0 = *reinterpret_cast<const float4*>(child + (size_t)(4 * p + 0) * D + kc);
    float4 a1 = *reinterpret_cast<const float4*>(child + (size_t)(4 * p + 0) * D + kc + 4);
    float4 b0 = *reinterpret_cast<const float4*>(child + (size_t)(4 * p + 1) * D + kc);
    float4 b1 = *reinterpret_cast<const float4*>(child + (size_t)(4 * p + 1) * D + kc + 4);
    float4 c0 = *reinterpret_cast<const float4*>(child + (size_t)(4 * p + 2) * D + kc);
    float4 c1 = *reinterpret_cast<const float4*>(child + (size_t)(4 * p + 2) * D + kc + 4);
    float4 d0 = *reinterpret_cast<const float4*>(child + (size_t)(4 * p + 3) * D + kc);
    float4 d1 = *reinterpret_cast<const float4*>(child + (size_t)(4 * p + 3) * D + kc + 4);
    float ca[8] = {a0.x, a0.y, a0.z, a0.w, a1.x, a1.y, a1.z, a1.w};
    float cb[8] = {b0.x, b0.y, b0.z, b0.w, b1.x, b1.y, b1.z, b1.w};
    float cc[8] = {c0.x, c0.y, c0.z, c0.w, c1.x, c1.y, c1.z, c1.w};
    float cd[8] = {d0.x, d0.y, d0.z, d0.w, d1.x, d1.y, d1.z, d1.w};
    short8 uh, ul, vh, vl;
#pragma unroll
    for (int j = 0; j < 8; ++j) {
        float u = ca[j] + c23 * cb[j] + c13 * cc[j];
        float v = c13 * cb[j] + c23 * cc[j] + cd[j];
        unsigned short h, l;
        split(u, h, l); uh[j] = (short)h; ul[j] = (short)l;
        split(v, h, l); vh[j] = (short)h; vl[j] = (short)l;
    }
    *reinterpret_cast<short8*>(&Ah[(size_t)p * KDIM + kc]) = uh;
    *reinterpret_cast<short8*>(&Al[(size_t)p * KDIM + kc]) = ul;
    *reinterpret_cast<short8*>(&Ah[(size_t)p * KDIM + 512 + kc]) = vh;
    *reinterpret_cast<short8*>(&Al[(size_t)p * KDIM + 512 + kc]) = vl;
}

// ---- MFMA GEMM (bf16x3 split) + tanh epilogue, fp32 h out ----
// C = Ah*Wh^T + Ah*Wl^T + Al*Wh^T ; h = tanh(x + C)
__global__ __launch_bounds__(256)
void gemm_tanh(const unsigned short* __restrict__ Ah, const unsigned short* __restrict__ Al,
               const unsigned short* __restrict__ Wh, const unsigned short* __restrict__ Wl,
               const float* __restrict__ x, float* __restrict__ hout, int n) {
    __shared__ __align__(16) unsigned short Ahs[128][64];
    __shared__ __align__(16) unsigned short Als[128][64];
    __shared__ __align__(16) unsigned short Bhs[128][64];
    __shared__ __align__(16) unsigned short Bls[128][64];
    const int m0 = blockIdx.x * 128;
    const int e0 = blockIdx.y * 128;
    const int tid = threadIdx.x;
    const int lane = tid & 63, wid = tid >> 6;
    const int wr = (wid >> 1) * 64, wc = (wid & 1) * 64;

    f32x4 acc[4][4];
#pragma unroll
    for (int m = 0; m < 4; ++m)
#pragma unroll
        for (int nn = 0; nn < 4; ++nn) acc[m][nn] = (f32x4){0.f, 0.f, 0.f, 0.f};

    const int sr = tid >> 3;          // 0..31
    const int skc = (tid & 7) << 3;   // 0,8,..,56

    for (int kb = 0; kb < KDIM; kb += 64) {
#pragma unroll
        for (int pass = 0; pass < 4; ++pass) {
            int rr = sr + pass * 32;
            size_t ga = (size_t)(m0 + rr) * KDIM + kb + skc;
            size_t gb = (size_t)(e0 + rr) * KDIM + kb + skc;
            *reinterpret_cast<short8*>(&Ahs[rr][skc]) = *reinterpret_cast<const short8*>(&Ah[ga]);
            *reinterpret_cast<short8*>(&Als[rr][skc]) = *reinterpret_cast<const short8*>(&Al[ga]);
            *reinterpret_cast<short8*>(&Bhs[rr][skc]) = *reinterpret_cast<const short8*>(&Wh[gb]);
            *reinterpret_cast<short8*>(&Bls[rr][skc]) = *reinterpret_cast<const short8*>(&Wl[gb]);
        }
        __syncthreads();
#pragma unroll
        for (int kk = 0; kk < 64; kk += 32) {
            const int ka = kk + ((lane >> 4) << 3);
            short8 afh[4], afl[4], bfh[4], bfl[4];
#pragma unroll
            for (int m = 0; m < 4; ++m) {
                afh[m] = *reinterpret_cast<const short8*>(&Ahs[wr + m * 16 + (lane & 15)][ka]);
                afl[m] = *reinterpret_cast<const short8*>(&Als[wr + m * 16 + (lane & 15)][ka]);
            }
#pragma unroll
            for (int nn = 0; nn < 4; ++nn) {
                bfh[nn] = *reinterpret_cast<const short8*>(&Bhs[wc + nn * 16 + (lane & 15)][ka]);
                bfl[nn] = *reinterpret_cast<const short8*>(&Bls[wc + nn * 16 + (lane & 15)][ka]);
            }
#pragma unroll
            for (int m = 0; m < 4; ++m)
#pragma unroll
                for (int nn = 0; nn < 4; ++nn) {
                    acc[m][nn] = __builtin_amdgcn_mfma_f32_16x16x32_bf16(afh[m], bfh[nn], acc[m][nn], 0, 0, 0);
                    acc[m][nn] = __builtin_amdgcn_mfma_f32_16x16x32_bf16(afh[m], bfl[nn], acc[m][nn], 0, 0, 0);
                    acc[m][nn] = __builtin_amdgcn_mfma_f32_16x16x32_bf16(afl[m], bfh[nn], acc[m][nn], 0, 0, 0);
                }
        }
        __syncthreads();
    }

    // epilogue: D frag mapping col=lane&15, row=4*(lane>>4)+reg
    const int dr = (lane >> 4) << 2;
    const int dc = lane & 15;
#pragma unroll
    for (int m = 0; m < 4; ++m) {
        int rbase = m0 + wr + m * 16 + dr;
#pragma unroll
        for (int j = 0; j < 4; ++j) {
            int row = rbase + j;
            if (row < n) {
#pragma unroll
                for (int nn = 0; nn < 4; ++nn) {
                    int col = e0 + wc + nn * 16 + dc;
                    float v = acc[m][nn][j] + x[(size_t)row * D + col];
                    hout[(size_t)row * D + col] = tanhf(v);
                }
            }
        }
    }
}

extern "C" void kernel_launch(void* const* d_in, const int* in_sizes, int n_in,
                              void* d_out, int out_size, void* d_ws, size_t ws_size,
                              hipStream_t stream) {
    const float* vectors = (const float*)d_in[0];
    const float* wl = (const float*)d_in[1];
    const float* wr = (const float*)d_in[2];
    float* out = (float*)d_out;

    char* ws = (char*)d_ws;
    unsigned short* Wh = (unsigned short*)ws;                        // 1 MB
    unsigned short* Wl = (unsigned short*)(ws + (1u << 20));         // 1 MB
    unsigned short* Ah = (unsigned short*)(ws + (2u << 20));         // 32 MB
    unsigned short* Al = (unsigned short*)(ws + (34u << 20));        // 32 MB
    float*          H0 = (float*)(ws + (66u << 20));                 // 32 MB (levels 7,5,3,1)
    float*          H1 = (float*)(ws + (98u << 20));                 // 8 MB  (levels 6,4,2)

    // level offsets / counts (B=4, depth=8)
    size_t off[10];
    int cnt[10];
    {
        size_t o = 0; int c = 1;
        for (int l = 0; l <= 8; ++l) { off[l] = o; cnt[l] = c; o += c; c *= 4; }
    }

    prep_w<<<2048, 256, 0, stream>>>(wl, wr, Wh, Wl);

    for (int l = 7; l >= 0; --l) {
        int n = cnt[l];
        int mpad = (n + 127) & ~127;
        int rblocks = (mpad * 64) / 256;
        const float* child = (l == 7) ? (vectors + off[8] * (size_t)D)
                                      : (((l + 1) & 1) ? H0 : H1);
        reduce_kernel<<<rblocks, 256, 0, stream>>>(child, Ah, Al, n, mpad);
        float* hout = (l == 0) ? out : ((l & 1) ? H0 : H1);
        const float* xv = vectors + off[l] * (size_t)D;
        dim3 grid(mpad / 128, 4);
        gemm_tanh<<<grid, 256, 0, stream>>>(Ah, Al, Wh, Wl, xv, hout, n);
    }
}

// Round 3
// 354.611 us; speedup vs baseline: 2.5983x; 2.5983x over previous
//
#include <hip/hip_runtime.h>

typedef short short8 __attribute__((ext_vector_type(8)));
typedef float f32x4 __attribute__((ext_vector_type(4)));

#define D 512
#define KDIM 1024

// ---- bf16 helpers (manual, RNE) ----
static __device__ __forceinline__ unsigned short f2b(float f) {
    unsigned u = __builtin_bit_cast(unsigned, f);
    unsigned r = (u + 0x7fffu + ((u >> 16) & 1u)) >> 16;
    return (unsigned short)r;
}
static __device__ __forceinline__ float b2f(unsigned short u) {
    return __builtin_bit_cast(float, ((unsigned)u) << 16);
}
static __device__ __forceinline__ void split(float v, unsigned short& hi, unsigned short& lo) {
    hi = f2b(v);
    lo = f2b(v - b2f(hi));
}

// ---- async global->LDS 16B per lane (linear dest: wave-uniform base + lane*16) ----
static __device__ __forceinline__ void g2lds(const void* g, void* l) {
    __builtin_amdgcn_global_load_lds(
        (const __attribute__((address_space(1))) unsigned int*)g,
        (__attribute__((address_space(3))) unsigned int*)l, 16, 0, 0);
}

// ---- build W hi/lo: W[e][k] bf16 pair, k<512 from wl, else wr ----
__global__ void prep_w(const float* __restrict__ wl, const float* __restrict__ wr,
                       unsigned short* __restrict__ Wh, unsigned short* __restrict__ Wl) {
    int t = blockIdx.x * 256 + threadIdx.x;   // over 512*1024
    int e = t >> 10, k = t & 1023;
    float v = (k < 512) ? wl[e * 512 + k] : wr[e * 512 + (k - 512)];
    unsigned short h, l;
    split(v, h, l);
    Wh[t] = h; Wl[t] = l;
}

// ---- child weighted reduce (fp32 in, bf16 hi/lo out) ----
// A[p][0:512]=U, A[p][512:1024]=V ; lc=[1,2/3,1/3,0], rc=[0,1/3,2/3,1]
__global__ void reduce_kernel(const float* __restrict__ child,
                              unsigned short* __restrict__ Ah, unsigned short* __restrict__ Al,
                              int n, int mpad) {
    int t = blockIdx.x * 256 + threadIdx.x;   // mpad*64 threads
    int p = t >> 6;
    int kc = (t & 63) << 3;
    if (p >= mpad) return;
    if (p >= n) {
        short8 z = (short8)0;
        *reinterpret_cast<short8*>(&Ah[(size_t)p * KDIM + kc]) = z;
        *reinterpret_cast<short8*>(&Ah[(size_t)p * KDIM + 512 + kc]) = z;
        *reinterpret_cast<short8*>(&Al[(size_t)p * KDIM + kc]) = z;
        *reinterpret_cast<short8*>(&Al[(size_t)p * KDIM + 512 + kc]) = z;
        return;
    }
    const float c13 = 1.0f / 3.0f, c23 = 2.0f / 3.0f;
    float4 a0 = *reinterpret_cast<const float4*>(child + (size_t)(4 * p + 0) * D + kc);
    float4 a1 = *reinterpret_cast<const float4*>(child + (size_t)(4 * p + 0) * D + kc + 4);
    float4 b0 = *reinterpret_cast<const float4*>(child + (size_t)(4 * p + 1) * D + kc);
    float4 b1 = *reinterpret_cast<const float4*>(child + (size_t)(4 * p + 1) * D + kc + 4);
    float4 c0 = *reinterpret_cast<const float4*>(child + (size_t)(4 * p + 2) * D + kc);
    float4 c1 = *reinterpret_cast<const float4*>(child + (size_t)(4 * p + 2) * D + kc + 4);
    float4 d0 = *reinterpret_cast<const float4*>(child + (size_t)(4 * p + 3) * D + kc);
    float4 d1 = *reinterpret_cast<const float4*>(child + (size_t)(4 * p + 3) * D + kc + 4);
    float ca[8] = {a0.x, a0.y, a0.z, a0.w, a1.x, a1.y, a1.z, a1.w};
    float cb[8] = {b0.x, b0.y, b0.z, b0.w, b1.x, b1.y, b1.z, b1.w};
    float cc[8] = {c0.x, c0.y, c0.z, c0.w, c1.x, c1.y, c1.z, c1.w};
    float cd[8] = {d0.x, d0.y, d0.z, d0.w, d1.x, d1.y, d1.z, d1.w};
    short8 uh, ul, vh, vl;
#pragma unroll
    for (int j = 0; j < 8; ++j) {
        float u = ca[j] + c23 * cb[j] + c13 * cc[j];
        float v = c13 * cb[j] + c23 * cc[j] + cd[j];
        unsigned short h, l;
        split(u, h, l); uh[j] = (short)h; ul[j] = (short)l;
        split(v, h, l); vh[j] = (short)h; vl[j] = (short)l;
    }
    *reinterpret_cast<short8*>(&Ah[(size_t)p * KDIM + kc]) = uh;
    *reinterpret_cast<short8*>(&Al[(size_t)p * KDIM + kc]) = ul;
    *reinterpret_cast<short8*>(&Ah[(size_t)p * KDIM + 512 + kc]) = vh;
    *reinterpret_cast<short8*>(&Al[(size_t)p * KDIM + 512 + kc]) = vl;
}

// ---- MFMA GEMM (bf16x3 split) + tanh epilogue, fp32 h out ----
// C = Ah*Wh^T + Ah*Wl^T + Al*Wh^T ; h = tanh(x + C)
// BM=128: 4 waves 2x2, wave 64x64 (4x4 frags).  BM=32: 4 waves 1x4 over N, wave 32x32 (2x2 frags).
template <int BM>
__global__ __launch_bounds__(256)
void gemm_tanh(const unsigned short* __restrict__ Ah, const unsigned short* __restrict__ Al,
               const unsigned short* __restrict__ Wh, const unsigned short* __restrict__ Wl,
               const float* __restrict__ x, float* __restrict__ hout, int n) {
    constexpr int MF = (BM == 128) ? 4 : 2;
    constexpr int NF = (BM == 128) ? 4 : 2;
    constexpr int APASS = BM / 32;
    __shared__ __align__(16) unsigned short Ahs[BM][64];
    __shared__ __align__(16) unsigned short Als[BM][64];
    __shared__ __align__(16) unsigned short Bhs[128][64];
    __shared__ __align__(16) unsigned short Bls[128][64];
    const int m0 = blockIdx.x * BM;
    const int e0 = blockIdx.y * 128;
    const int tid = threadIdx.x;
    const int lane = tid & 63, wid = tid >> 6;
    const int wr = (BM == 128) ? ((wid >> 1) * 64) : 0;
    const int wc = (BM == 128) ? ((wid & 1) * 64) : (wid * 32);

    f32x4 acc[MF][NF];
#pragma unroll
    for (int m = 0; m < MF; ++m)
#pragma unroll
        for (int nn = 0; nn < NF; ++nn) acc[m][nn] = (f32x4){0.f, 0.f, 0.f, 0.f};

    const int lrow = lane >> 3;        // 0..7
    const int lcol = (lane & 7) << 3;  // elem col 0,8,..,56

    for (int kb = 0; kb < KDIM; kb += 64) {
        // stage A tiles (BM rows) and B tiles (128 rows), 16B/lane DMA
#pragma unroll
        for (int p = 0; p < APASS; ++p) {
            int row = p * 32 + wid * 8;
            size_t g = (size_t)(m0 + row + lrow) * KDIM + kb + lcol;
            g2lds(&Ah[g], &Ahs[row][0]);
            g2lds(&Al[g], &Als[row][0]);
        }
#pragma unroll
        for (int p = 0; p < 4; ++p) {
            int row = p * 32 + wid * 8;
            size_t g = (size_t)(e0 + row + lrow) * KDIM + kb + lcol;
            g2lds(&Wh[g], &Bhs[row][0]);
            g2lds(&Wl[g], &Bls[row][0]);
        }
        __syncthreads();
#pragma unroll
        for (int kk = 0; kk < 64; kk += 32) {
            const int ka = kk + ((lane >> 4) << 3);
            short8 afh[MF], afl[MF], bfh[NF], bfl[NF];
#pragma unroll
            for (int m = 0; m < MF; ++m) {
                afh[m] = *reinterpret_cast<const short8*>(&Ahs[wr + m * 16 + (lane & 15)][ka]);
                afl[m] = *reinterpret_cast<const short8*>(&Als[wr + m * 16 + (lane & 15)][ka]);
            }
#pragma unroll
            for (int nn = 0; nn < NF; ++nn) {
                bfh[nn] = *reinterpret_cast<const short8*>(&Bhs[wc + nn * 16 + (lane & 15)][ka]);
                bfl[nn] = *reinterpret_cast<const short8*>(&Bls[wc + nn * 16 + (lane & 15)][ka]);
            }
#pragma unroll
            for (int m = 0; m < MF; ++m)
#pragma unroll
                for (int nn = 0; nn < NF; ++nn) {
                    acc[m][nn] = __builtin_amdgcn_mfma_f32_16x16x32_bf16(afh[m], bfh[nn], acc[m][nn], 0, 0, 0);
                    acc[m][nn] = __builtin_amdgcn_mfma_f32_16x16x32_bf16(afh[m], bfl[nn], acc[m][nn], 0, 0, 0);
                    acc[m][nn] = __builtin_amdgcn_mfma_f32_16x16x32_bf16(afl[m], bfh[nn], acc[m][nn], 0, 0, 0);
                }
        }
        __syncthreads();
    }

    // epilogue: D frag mapping col=lane&15, row=4*(lane>>4)+reg
    const int dr = (lane >> 4) << 2;
    const int dc = lane & 15;
#pragma unroll
    for (int m = 0; m < MF; ++m) {
        int rbase = m0 + wr + m * 16 + dr;
#pragma unroll
        for (int j = 0; j < 4; ++j) {
            int row = rbase + j;
            if (row < n) {
#pragma unroll
                for (int nn = 0; nn < NF; ++nn) {
                    int col = e0 + wc + nn * 16 + dc;
                    float v = acc[m][nn][j] + x[(size_t)row * D + col];
                    hout[(size_t)row * D + col] = tanhf(v);
                }
            }
        }
    }
}

extern "C" void kernel_launch(void* const* d_in, const int* in_sizes, int n_in,
                              void* d_out, int out_size, void* d_ws, size_t ws_size,
                              hipStream_t stream) {
    const float* vectors = (const float*)d_in[0];
    const float* wl = (const float*)d_in[1];
    const float* wr = (const float*)d_in[2];
    float* out = (float*)d_out;

    char* ws = (char*)d_ws;
    unsigned short* Wh = (unsigned short*)ws;                        // 1 MB
    unsigned short* Wl = (unsigned short*)(ws + (1u << 20));         // 1 MB
    unsigned short* Ah = (unsigned short*)(ws + (2u << 20));         // 32 MB
    unsigned short* Al = (unsigned short*)(ws + (34u << 20));        // 32 MB
    float*          H0 = (float*)(ws + (66u << 20));                 // 32 MB (levels 7,5,3,1)
    float*          H1 = (float*)(ws + (98u << 20));                 // 8 MB  (levels 6,4,2)

    // level offsets / counts (B=4, depth=8)
    size_t off[10];
    int cnt[10];
    {
        size_t o = 0; int c = 1;
        for (int l = 0; l <= 8; ++l) { off[l] = o; cnt[l] = c; o += c; c *= 4; }
    }

    prep_w<<<2048, 256, 0, stream>>>(wl, wr, Wh, Wl);

    for (int l = 7; l >= 0; --l) {
        int n = cnt[l];
        int mpad = (n + 127) & ~127;
        int rblocks = (mpad * 64) / 256;
        const float* child = (l == 7) ? (vectors + off[8] * (size_t)D)
                                      : (((l + 1) & 1) ? H0 : H1);
        reduce_kernel<<<rblocks, 256, 0, stream>>>(child, Ah, Al, n, mpad);
        float* hout = (l == 0) ? out : ((l & 1) ? H0 : H1);
        const float* xv = vectors + off[l] * (size_t)D;
        if (n >= 2048) {
            dim3 grid(mpad / 128, 4);
            gemm_tanh<128><<<grid, 256, 0, stream>>>(Ah, Al, Wh, Wl, xv, hout, n);
        } else {
            int gx = ((n + 31) & ~31) / 32;
            dim3 grid(gx, 4);
            gemm_tanh<32><<<grid, 256, 0, stream>>>(Ah, Al, Wh, Wl, xv, hout, n);
        }
    }
}

// Round 4
// 328.865 us; speedup vs baseline: 2.8018x; 1.0783x over previous
//
#include <hip/hip_runtime.h>

typedef short short8 __attribute__((ext_vector_type(8)));
typedef float f32x4 __attribute__((ext_vector_type(4)));

#define D 512
#define KDIM 1024

// ---- bf16 helpers (manual, RNE) ----
static __device__ __forceinline__ unsigned short f2b(float f) {
    unsigned u = __builtin_bit_cast(unsigned, f);
    unsigned r = (u + 0x7fffu + ((u >> 16) & 1u)) >> 16;
    return (unsigned short)r;
}
static __device__ __forceinline__ float b2f(unsigned short u) {
    return __builtin_bit_cast(float, ((unsigned)u) << 16);
}
static __device__ __forceinline__ void split(float v, unsigned short& hi, unsigned short& lo) {
    hi = f2b(v);
    lo = f2b(v - b2f(hi));
}

// ---- async global->LDS 16B per lane (linear dest: wave-uniform base + lane*16) ----
static __device__ __forceinline__ void g2lds(const void* g, void* l) {
    __builtin_amdgcn_global_load_lds(
        (const __attribute__((address_space(1))) unsigned int*)g,
        (__attribute__((address_space(3))) unsigned int*)l, 16, 0, 0);
}

// ---- build W hi/lo: W[e][k] bf16 pair, k<512 from wl, else wr ----
__global__ void prep_w(const float* __restrict__ wl, const float* __restrict__ wr,
                       unsigned short* __restrict__ Wh, unsigned short* __restrict__ Wl) {
    int t = blockIdx.x * 256 + threadIdx.x;   // over 512*1024
    int e = t >> 10, k = t & 1023;
    float v = (k < 512) ? wl[e * 512 + k] : wr[e * 512 + (k - 512)];
    unsigned short h, l;
    split(v, h, l);
    Wh[t] = h; Wl[t] = l;
}

// ---- zero pad slivers: 96 blocks x 256 threads x 16B = 384 KiB at base ----
__global__ void zero_region(unsigned short* __restrict__ base) {
    int t = blockIdx.x * 256 + threadIdx.x;
    *reinterpret_cast<short8*>(base + (size_t)t * 8) = (short8)0;
}

// ---- leaf weighted reduce (fp32 leaves -> bf16 hi/lo A7) ----
// A[p][0:512]=U, A[p][512:1024]=V ; lc=[1,2/3,1/3,0], rc=[0,1/3,2/3,1]
__global__ void reduce_kernel(const float* __restrict__ child,
                              unsigned short* __restrict__ Ah, unsigned short* __restrict__ Al,
                              int n) {
    int t = blockIdx.x * 256 + threadIdx.x;   // n*64 threads
    int p = t >> 6;
    int kc = (t & 63) << 3;
    if (p >= n) return;
    const float c13 = 1.0f / 3.0f, c23 = 2.0f / 3.0f;
    float4 a0 = *reinterpret_cast<const float4*>(child + (size_t)(4 * p + 0) * D + kc);
    float4 a1 = *reinterpret_cast<const float4*>(child + (size_t)(4 * p + 0) * D + kc + 4);
    float4 b0 = *reinterpret_cast<const float4*>(child + (size_t)(4 * p + 1) * D + kc);
    float4 b1 = *reinterpret_cast<const float4*>(child + (size_t)(4 * p + 1) * D + kc + 4);
    float4 c0 = *reinterpret_cast<const float4*>(child + (size_t)(4 * p + 2) * D + kc);
    float4 c1 = *reinterpret_cast<const float4*>(child + (size_t)(4 * p + 2) * D + kc + 4);
    float4 d0 = *reinterpret_cast<const float4*>(child + (size_t)(4 * p + 3) * D + kc);
    float4 d1 = *reinterpret_cast<const float4*>(child + (size_t)(4 * p + 3) * D + kc + 4);
    float ca[8] = {a0.x, a0.y, a0.z, a0.w, a1.x, a1.y, a1.z, a1.w};
    float cb[8] = {b0.x, b0.y, b0.z, b0.w, b1.x, b1.y, b1.z, b1.w};
    float cc[8] = {c0.x, c0.y, c0.z, c0.w, c1.x, c1.y, c1.z, c1.w};
    float cd[8] = {d0.x, d0.y, d0.z, d0.w, d1.x, d1.y, d1.z, d1.w};
    short8 uh, ul, vh, vl;
#pragma unroll
    for (int j = 0; j < 8; ++j) {
        float u = ca[j] + c23 * cb[j] + c13 * cc[j];
        float v = c13 * cb[j] + c23 * cc[j] + cd[j];
        unsigned short h, l;
        split(u, h, l); uh[j] = (short)h; ul[j] = (short)l;
        split(v, h, l); vh[j] = (short)h; vl[j] = (short)l;
    }
    *reinterpret_cast<short8*>(&Ah[(size_t)p * KDIM + kc]) = uh;
    *reinterpret_cast<short8*>(&Al[(size_t)p * KDIM + kc]) = ul;
    *reinterpret_cast<short8*>(&Ah[(size_t)p * KDIM + 512 + kc]) = vh;
    *reinterpret_cast<short8*>(&Al[(size_t)p * KDIM + 512 + kc]) = vl;
}

// ---- MFMA GEMM (bf16x3 split) + tanh + fused next-level child-reduce ----
// C = Ah*Wh^T + Ah*Wl^T + Al*Wh^T ; h = tanh(x + C)
// Epilogue: each lane's 4 acc rows (rbase..rbase+3) are the 4 children of parent
// p = rbase/4 -> compute U,V per-lane, split bf16 hi/lo, write next A. FINAL -> fp32 out.
template <int BM, bool FINAL>
__global__ __launch_bounds__(256)
void gemm_tanh(const unsigned short* __restrict__ Ah, const unsigned short* __restrict__ Al,
               const unsigned short* __restrict__ Wh, const unsigned short* __restrict__ Wl,
               const float* __restrict__ x,
               unsigned short* __restrict__ nAh, unsigned short* __restrict__ nAl,
               float* __restrict__ out, int n) {
    constexpr int MF = (BM == 128) ? 4 : 2;
    constexpr int NF = (BM == 128) ? 4 : 2;
    constexpr int APASS = BM / 32;
    __shared__ __align__(16) unsigned short Ahs[BM][64];
    __shared__ __align__(16) unsigned short Als[BM][64];
    __shared__ __align__(16) unsigned short Bhs[128][64];
    __shared__ __align__(16) unsigned short Bls[128][64];
    const int m0 = blockIdx.x * BM;
    const int e0 = blockIdx.y * 128;
    const int tid = threadIdx.x;
    const int lane = tid & 63, wid = tid >> 6;
    const int wr = (BM == 128) ? ((wid >> 1) * 64) : 0;
    const int wc = (BM == 128) ? ((wid & 1) * 64) : (wid * 32);

    f32x4 acc[MF][NF];
#pragma unroll
    for (int m = 0; m < MF; ++m)
#pragma unroll
        for (int nn = 0; nn < NF; ++nn) acc[m][nn] = (f32x4){0.f, 0.f, 0.f, 0.f};

    const int lrow = lane >> 3;        // 0..7
    const int lcol = (lane & 7) << 3;  // elem col 0,8,..,56

    for (int kb = 0; kb < KDIM; kb += 64) {
        // stage A tiles (BM rows) and B tiles (128 rows), 16B/lane DMA
#pragma unroll
        for (int p = 0; p < APASS; ++p) {
            int row = p * 32 + wid * 8;
            size_t g = (size_t)(m0 + row + lrow) * KDIM + kb + lcol;
            g2lds(&Ah[g], &Ahs[row][0]);
            g2lds(&Al[g], &Als[row][0]);
        }
#pragma unroll
        for (int p = 0; p < 4; ++p) {
            int row = p * 32 + wid * 8;
            size_t g = (size_t)(e0 + row + lrow) * KDIM + kb + lcol;
            g2lds(&Wh[g], &Bhs[row][0]);
            g2lds(&Wl[g], &Bls[row][0]);
        }
        __syncthreads();
#pragma unroll
        for (int kk = 0; kk < 64; kk += 32) {
            const int ka = kk + ((lane >> 4) << 3);
            short8 afh[MF], afl[MF], bfh[NF], bfl[NF];
#pragma unroll
            for (int m = 0; m < MF; ++m) {
                afh[m] = *reinterpret_cast<const short8*>(&Ahs[wr + m * 16 + (lane & 15)][ka]);
                afl[m] = *reinterpret_cast<const short8*>(&Als[wr + m * 16 + (lane & 15)][ka]);
            }
#pragma unroll
            for (int nn = 0; nn < NF; ++nn) {
                bfh[nn] = *reinterpret_cast<const short8*>(&Bhs[wc + nn * 16 + (lane & 15)][ka]);
                bfl[nn] = *reinterpret_cast<const short8*>(&Bls[wc + nn * 16 + (lane & 15)][ka]);
            }
#pragma unroll
            for (int m = 0; m < MF; ++m)
#pragma unroll
                for (int nn = 0; nn < NF; ++nn) {
                    acc[m][nn] = __builtin_amdgcn_mfma_f32_16x16x32_bf16(afh[m], bfh[nn], acc[m][nn], 0, 0, 0);
                    acc[m][nn] = __builtin_amdgcn_mfma_f32_16x16x32_bf16(afh[m], bfl[nn], acc[m][nn], 0, 0, 0);
                    acc[m][nn] = __builtin_amdgcn_mfma_f32_16x16x32_bf16(afl[m], bfh[nn], acc[m][nn], 0, 0, 0);
                }
        }
        __syncthreads();
    }

    // epilogue: D frag mapping col=lane&15, row=4*(lane>>4)+reg
    const int dr = (lane >> 4) << 2;
    const int dc = lane & 15;
    const float c13 = 1.0f / 3.0f, c23 = 2.0f / 3.0f;
#pragma unroll
    for (int m = 0; m < MF; ++m) {
        int rbase = m0 + wr + m * 16 + dr;
        if (rbase >= n) continue;   // whole 4-row group OOB (n is a multiple of 4, or FINAL n==1)
#pragma unroll
        for (int nn = 0; nn < NF; ++nn) {
            int col = e0 + wc + nn * 16 + dc;
            float hv[4];
#pragma unroll
            for (int j = 0; j < 4; ++j) {
                int row = rbase + j;
                hv[j] = (row < n) ? tanhf(acc[m][nn][j] + x[(size_t)row * D + col]) : 0.f;
            }
            if (FINAL) {
                if (rbase == 0) out[col] = hv[0];
            } else {
                int p = rbase >> 2;
                float u = hv[0] + c23 * hv[1] + c13 * hv[2];
                float v = c13 * hv[1] + c23 * hv[2] + hv[3];
                unsigned short h_, l_;
                split(u, h_, l_);
                nAh[(size_t)p * KDIM + col] = h_;
                nAl[(size_t)p * KDIM + col] = l_;
                split(v, h_, l_);
                nAh[(size_t)p * KDIM + 512 + col] = h_;
                nAl[(size_t)p * KDIM + 512 + col] = l_;
            }
        }
    }
}

extern "C" void kernel_launch(void* const* d_in, const int* in_sizes, int n_in,
                              void* d_out, int out_size, void* d_ws, size_t ws_size,
                              hipStream_t stream) {
    const float* vectors = (const float*)d_in[0];
    const float* wl = (const float*)d_in[1];
    const float* wr = (const float*)d_in[2];
    float* out = (float*)d_out;
    char* ws = (char*)d_ws;

    size_t cur = 0;
    auto alloc = [&](size_t bytes) -> char* {
        char* p = ws + cur;
        cur += (bytes + 255) & ~(size_t)255;
        return p;
    };
    unsigned short* Wh = (unsigned short*)alloc((size_t)512 * 1024 * 2);
    unsigned short* Wl = (unsigned short*)alloc((size_t)512 * 1024 * 2);
    // A-region padded rows per level (gemm read coverage), level index 0..7
    const int arows[8] = {32, 32, 32, 64, 256, 1024, 4096, 16384};
    unsigned short *Ah[8], *Al[8];
    for (int l = 7; l >= 0; --l) {
        Ah[l] = (unsigned short*)alloc((size_t)arows[l] * KDIM * 2);
        Al[l] = (unsigned short*)alloc((size_t)arows[l] * KDIM * 2);
    }
    // levels 2,1,0 allocated last & contiguously: 6 x 64KiB = 384 KiB sliver region

    // level start offsets in `vectors`: (4^l - 1)/3
    size_t off[9];
    {
        size_t o = 0; size_t c = 1;
        for (int l = 0; l <= 8; ++l) { off[l] = o; o += c; c *= 4; }
    }

    prep_w<<<2048, 256, 0, stream>>>(wl, wr, Wh, Wl);
    zero_region<<<96, 256, 0, stream>>>(Ah[2]);  // zeros A2,A1,A0 (hi+lo) fully

    // leaf reduce: 65536 leaves -> A7 (16384 parents), exact coverage
    reduce_kernel<<<(16384 * 64) / 256, 256, 0, stream>>>(
        vectors + off[8] * (size_t)D, Ah[7], Al[7], 16384);

    for (int l = 7; l >= 1; --l) {
        int n = 1 << (2 * l);
        const float* xv = vectors + off[l] * (size_t)D;
        if (n >= 4096) {
            dim3 grid(n / 128, 4);
            gemm_tanh<128, false><<<grid, 256, 0, stream>>>(
                Ah[l], Al[l], Wh, Wl, xv, Ah[l - 1], Al[l - 1], nullptr, n);
        } else {
            int gx = (n + 31) / 32;
            dim3 grid(gx, 4);
            gemm_tanh<32, false><<<grid, 256, 0, stream>>>(
                Ah[l], Al[l], Wh, Wl, xv, Ah[l - 1], Al[l - 1], nullptr, n);
        }
    }
    // final level 0: single node, fp32 out
    gemm_tanh<32, true><<<dim3(1, 4), 256, 0, stream>>>(
        Ah[0], Al[0], Wh, Wl, vectors, nullptr, nullptr, out, 1);
}